// Round 16
// baseline (17.229 us; speedup 1.0000x reference)
//
#include <hip/hip_runtime.h>

#define GX 512
#define NF 32
#define XD 1024

#define CELLB 64                 // f16 cell = 32 feats * 2 B
#define NCELL 33                 // 32 cells + boundary
#define RROWB (NCELL * CELLB)    // 2112 B per staged row
#define WRAWB (2 * RROWB)        // per-wave private staging: 2 rows = 4224 B
#define LDSBYTES (4 * WRAWB)     // 16896 B

typedef _Float16 half8 __attribute__((ext_vector_type(8)));
typedef __fp16  fp16x2 __attribute__((ext_vector_type(2)));
typedef float  floatx4 __attribute__((ext_vector_type(4)));

union PkU { fp16x2 h; unsigned u; };
union FragU { half8 h; uint4 u4; fp16x2 p[4]; unsigned u[4]; };

__device__ __forceinline__ unsigned pkrtz(float a, float b) {
    PkU x; x.h = __builtin_amdgcn_cvt_pkrtz(a, b); return x.u;
}
__device__ __forceinline__ unsigned relu_pk(unsigned s) {
    unsigned r;
    asm("v_pk_max_f16 %0, %1, 0" : "=v"(r) : "v"(s));
    return r;
}

// BARRIER-FREE: each wave stages its own 2 grid rows into private LDS and
// proceeds with only same-wave in-order DS dependencies. No __syncthreads.
// G stays in registers (R15): pixel tiles = same-parity columns; layer-2
// A-frag k-slots pi-permuted so G's C/D quads ARE the layer-2 B-frag after
// f32 interp + relu/pack.
__global__ __launch_bounds__(256, 4) void t3d_main(
    const float* __restrict__ data,
    const float* __restrict__ W1, const float* __restrict__ b1,
    const float* __restrict__ W2, const float* __restrict__ b2,
    const float* __restrict__ W3, const float* __restrict__ b3,
    float* __restrict__ out)
{
    __shared__ uint4 lds4[LDSBYTES / 16];

    const int tid  = threadIdx.x;
    const int wid  = tid >> 6;
    const int lane = tid & 63;
    const int c = lane & 15, g = lane >> 4;

    // XCD swizzle: 2048 wgs, 8 XCDs, 256 contiguous per XCD (bijective)
    const int bid = blockIdx.x;
    const int wg  = (bid & 7) * 256 + (bid >> 3);
    const int RB  = wg >> 4;          // row-block: image rows 8RB..8RB+7
    const int cbk = wg & 15;          // 64-pixel column block
    const int XB  = 32 * cbk;         // first grid cell
    const int YB  = 4 * RB;           // first grid row

    unsigned char* praw = (unsigned char*)lds4 + wid * WRAWB;

    // ---- wave-private staging: 2 grid rows x 33 cells, f32 -> f16 ----------
    const int cl8 = lane >> 3, fl = lane & 7;    // 8 lanes per cell
#pragma unroll
    for (int rl = 0; rl < 2; ++rl) {
        const int y = min(YB + wid + rl, GX - 1);
        const float* rowp = data + (size_t)y * (GX * NF);
        floatx4 v[4];
#pragma unroll
        for (int k = 0; k < 4; ++k)
            v[k] = *(const floatx4*)(rowp + (XB + 8 * k + cl8) * NF + 4 * fl);
        floatx4 vb;
        if (lane < 8)
            vb = *(const floatx4*)(rowp + min(XB + 32, GX - 1) * NF + 4 * lane);
#pragma unroll
        for (int k = 0; k < 4; ++k) {
            const int cell = 8 * k + cl8;
            uint2 u = { pkrtz(v[k][0], v[k][1]), pkrtz(v[k][2], v[k][3]) };
            *(uint2*)(praw + rl * RROWB + cell * CELLB
                      + (((fl >> 1) ^ ((cell >> 1) & 3)) << 4) + ((fl & 1) << 3)) = u;
        }
        if (lane < 8) {
            uint2 u = { pkrtz(vb[0], vb[1]), pkrtz(vb[2], vb[3]) };
            *(uint2*)(praw + rl * RROWB + 32 * CELLB
                      + ((lane >> 1) << 4) + ((lane & 1) << 3)) = u;
        }
    }

    // ---- weight fragments ---------------------------------------------------
    // aw1: standard k-mapping. aw2: PI-PERMUTED k-slots (R15 verbatim).
    FragU aw1[2], aw2[2]; floatx4 bia1[2], bia2[2], w3f[2];
#pragma unroll
    for (int jt = 0; jt < 2; ++jt) {
#pragma unroll
        for (int w = 0; w < 4; ++w)
            aw1[jt].u[w] = pkrtz(W1[(8*g+2*w)*NF + 16*jt + c], W1[(8*g+2*w+1)*NF + 16*jt + c]);
        aw2[jt].u[0] = pkrtz(W2[(4*g+0)*NF + 16*jt + c],  W2[(4*g+1)*NF + 16*jt + c]);
        aw2[jt].u[1] = pkrtz(W2[(4*g+2)*NF + 16*jt + c],  W2[(4*g+3)*NF + 16*jt + c]);
        aw2[jt].u[2] = pkrtz(W2[(16+4*g+0)*NF + 16*jt + c], W2[(16+4*g+1)*NF + 16*jt + c]);
        aw2[jt].u[3] = pkrtz(W2[(16+4*g+2)*NF + 16*jt + c], W2[(16+4*g+3)*NF + 16*jt + c]);
        bia1[jt] = ((const floatx4*)b1)[4*jt + g];
        bia2[jt] = ((const floatx4*)b2)[4*jt + g];
        w3f[jt]  = ((const floatx4*)W3)[4*jt + g];
    }

    // NO BARRIER: same-wave ds_write -> ds_read is in-order.

#define RD(rl, cell) (*(const uint4*)(praw + (rl) * RROWB + (cell) * CELLB \
                      + ((g ^ (((cell) >> 1) & 3)) << 4)))

    float ss[8];
    // wave = image rows {2(4RB+wid) ... }: grid rows wid (local 0), wid+1 (local 1)
#pragma unroll
    for (int s = 0; s < 2; ++s) {
        const int c0 = 16 * s + c;
        FragU Bat, Bst, Bab, Bsb;
        Bat.u4 = RD(0, c0);      // aligned, top row
        Bst.u4 = RD(0, c0 + 1);  // shifted (x1), top
        Bab.u4 = RD(1, c0);      // aligned, bottom
        Bsb.u4 = RD(1, c0 + 1);  // shifted, bottom
        floatx4 GTA0 = __builtin_amdgcn_mfma_f32_16x16x32_f16(aw1[0].h, Bat.h, bia1[0], 0, 0, 0);
        floatx4 GTA1 = __builtin_amdgcn_mfma_f32_16x16x32_f16(aw1[1].h, Bat.h, bia1[1], 0, 0, 0);
        floatx4 GTS0 = __builtin_amdgcn_mfma_f32_16x16x32_f16(aw1[0].h, Bst.h, bia1[0], 0, 0, 0);
        floatx4 GTS1 = __builtin_amdgcn_mfma_f32_16x16x32_f16(aw1[1].h, Bst.h, bia1[1], 0, 0, 0);
        floatx4 GBA0 = __builtin_amdgcn_mfma_f32_16x16x32_f16(aw1[0].h, Bab.h, bia1[0], 0, 0, 0);
        floatx4 GBA1 = __builtin_amdgcn_mfma_f32_16x16x32_f16(aw1[1].h, Bab.h, bia1[1], 0, 0, 0);
        floatx4 GBS0 = __builtin_amdgcn_mfma_f32_16x16x32_f16(aw1[0].h, Bsb.h, bia1[0], 0, 0, 0);
        floatx4 GBS1 = __builtin_amdgcn_mfma_f32_16x16x32_f16(aw1[1].h, Bsb.h, bia1[1], 0, 0, 0);

#pragma unroll
        for (int rr = 0; rr < 2; ++rr) {       // image-row parity (y lerp)
#pragma unroll
            for (int tp = 0; tp < 2; ++tp) {   // column parity (x lerp)
                const float w0v = tp ? 0.75f : 0.25f;
                const float w1v = rr ? 0.75f : 0.25f;
                const float wA = (1.0f - w0v) * (1.0f - w1v);
                const float wB = w0v * (1.0f - w1v);
                const float wC = (1.0f - w0v) * w1v;
                const float wD = w0v * w1v;
                floatx4 d0 = wA * GTA0 + wB * GTS0 + wC * GBA0 + wD * GBS0;
                floatx4 d1 = wA * GTA1 + wB * GTS1 + wC * GBA1 + wD * GBS1;
                FragU f;
                f.u[0] = relu_pk(pkrtz(d0[0], d0[1]));
                f.u[1] = relu_pk(pkrtz(d0[2], d0[3]));
                f.u[2] = relu_pk(pkrtz(d1[0], d1[1]));
                f.u[3] = relu_pk(pkrtz(d1[2], d1[3]));
                floatx4 e0 = __builtin_amdgcn_mfma_f32_16x16x32_f16(aw2[0].h, f.h, bia2[0], 0, 0, 0);
                floatx4 e1 = __builtin_amdgcn_mfma_f32_16x16x32_f16(aw2[1].h, f.h, bia2[1], 0, 0, 0);
                float t = 0.0f;
#pragma unroll
                for (int r = 0; r < 4; ++r) {
                    t = fmaf(fmaxf(e0[r], 0.0f), w3f[0][r], t);
                    t = fmaf(fmaxf(e1[r], 0.0f), w3f[1][r], t);
                }
                ss[(rr << 2) + (s << 1) + tp] = t;
            }
        }
    }
#undef RD

    // ---- batched reduction over g-groups (verified pattern) ----------------
    const bool lo = (lane < 32);
    float tt[4];
#pragma unroll
    for (int k = 0; k < 4; ++k) {
        const float x  = lo ? ss[4 + k] : ss[k];
        const float rv = __shfl_xor(x, 32, 64);
        tt[k] = (lo ? ss[k] : ss[4 + k]) + rv;
    }
    const bool go = (g & 1);
    const float u0 = go ? tt[0] : tt[2];
    const float r0 = __shfl_xor(u0, 16, 64);
    const float fin0 = (go ? tt[2] : tt[0]) + r0;
    const float u1 = go ? tt[1] : tt[3];
    const float r1 = __shfl_xor(u1, 16, 64);
    const float fin1 = (go ? tt[3] : tt[1]) + r1;

    // lane (g,c): row 2wid+(g>>1), cols 32(g&1)+2c, +2c+1 (contiguous float2)
    const float b3v = b3[0];
    const int orow = 8 * RB + 2 * wid + (g >> 1);
    const int ocol = 64 * cbk + 32 * (g & 1) + 2 * c;
    float2 o2 = { fin0 + b3v, fin1 + b3v };
    *(float2*)(out + (size_t)orow * XD + ocol) = o2;
}

extern "C" void kernel_launch(void* const* d_in, const int* in_sizes, int n_in,
                              void* d_out, int out_size, void* d_ws, size_t ws_size,
                              hipStream_t stream) {
    // inputs: z, data, W1, b1, W2, b2, W3, b3, x0, y0, x1, y1, lerp_weights
    const float* data = (const float*)d_in[1];
    const float* W1   = (const float*)d_in[2];
    const float* b1   = (const float*)d_in[3];
    const float* W2   = (const float*)d_in[4];
    const float* b2   = (const float*)d_in[5];
    const float* W3   = (const float*)d_in[6];
    const float* b3   = (const float*)d_in[7];
    float* out = (float*)d_out;
    (void)d_ws; (void)ws_size;

    const int blocks = 2048;   // 128 row-blocks x 16 col-blocks
    hipLaunchKernelGGL(t3d_main, dim3(blocks), dim3(256), 0, stream,
                       data, W1, b1, W2, b2, W3, b3, out);
}